// Round 1
// baseline (224.855 us; speedup 1.0000x reference)
//
#include <hip/hip_runtime.h>
#include <math.h>

#define EPSBN 1e-5f

constexpr int B_ = 8, C_ = 256, N_ = 4096, IMG_ = 64;
constexpr int HEADS_ = 4, K_ = 16, VV_ = 64, M_ = 11, OC_ = 144;

// workspace layout (float offsets)
constexpr size_t O_WT   = 0;                                   // WcatT[256][144]
constexpr size_t O_BIAS = 36864;                               // [144]
constexpr size_t O_EMBT = 37120;                               // embT[121][16]
constexpr size_t O_Q    = 39424;                               // [8][64][4096]
constexpr size_t O_KEYS = O_Q    + (size_t)B_ * 64 * N_;       // [8][16][4096]
constexpr size_t O_SM   = O_KEYS + (size_t)B_ * 16 * N_;       // [8][16][4096]
constexpr size_t O_VALS = O_SM   + (size_t)B_ * 16 * N_;       // [8][64][4096]
constexpr size_t O_VALT = O_VALS + (size_t)B_ * 64 * N_;       // [8][4096][64]
constexpr size_t O_LCP  = O_VALT + (size_t)B_ * (size_t)N_ * 64; // [8][16][16][64]
constexpr size_t O_LC   = O_LCP  + (size_t)B_ * 16 * 16 * 64;  // [8][16][64]

// ---------------- K0: fold BN into weights, transpose emb ----------------
__global__ void k_prep(const float* __restrict__ Wq,
                       const float* __restrict__ qg, const float* __restrict__ qb,
                       const float* __restrict__ qm, const float* __restrict__ qv,
                       const float* __restrict__ Wk, const float* __restrict__ Wv,
                       const float* __restrict__ vg, const float* __restrict__ vb,
                       const float* __restrict__ vm, const float* __restrict__ vva,
                       const float* __restrict__ emb, float* __restrict__ ws) {
    int t = threadIdx.x;
    // WcatT[c][o] = W[o][c] * scale[o]
    for (int idx = t; idx < 256 * 144; idx += 256) {
        int c = idx / 144, o = idx % 144;
        float w;
        if (o < 64) {
            float s = qg[o] * rsqrtf(qv[o] + EPSBN);
            w = Wq[o * 256 + c] * s;
        } else if (o < 80) {
            w = Wk[(o - 64) * 256 + c];
        } else {
            int ov = o - 80;
            float s = vg[ov] * rsqrtf(vva[ov] + EPSBN);
            w = Wv[ov * 256 + c] * s;
        }
        ws[O_WT + idx] = w;
    }
    if (t < 144) {
        float bias;
        if (t < 64) {
            float s = qg[t] * rsqrtf(qv[t] + EPSBN);
            bias = qb[t] - qm[t] * s;
        } else if (t < 80) {
            bias = 0.f;
        } else {
            int ov = t - 80;
            float s = vg[ov] * rsqrtf(vva[ov] + EPSBN);
            bias = vb[ov] - vm[ov] * s;
        }
        ws[O_BIAS + t] = bias;
    }
    // embT[tap][k] = emb[k][tap]
    for (int idx = t; idx < 121 * 16; idx += 256) {
        int tap = idx / 16, k = idx % 16;
        ws[O_EMBT + idx] = emb[k * 121 + tap];
    }
}

// ---------------- K1: fused q/k/v projection (GEMM 144x256 x 256xN) ------
__global__ __launch_bounds__(256) void k_proj(const float* __restrict__ x,
                                              const float* __restrict__ wsc,
                                              float* __restrict__ ws) {
    __shared__ float xs[256 * 64];   // x[c][pos] tile, 64KB
    int b    = blockIdx.x >> 6;
    int pos0 = (blockIdx.x & 63) * 64;
    int t    = threadIdx.x;

    // cooperative load: 16384 floats as float4
    for (int i = 0; i < 16; i++) {
        int f4 = t + i * 256;            // 4096 float4s
        int c  = f4 >> 4, p4 = f4 & 15;
        float4 v = *(const float4*)(x + ((size_t)(b * 256 + c)) * N_ + pos0 + p4 * 4);
        *(float4*)(xs + c * 64 + p4 * 4) = v;
    }
    __syncthreads();

    int wv   = __builtin_amdgcn_readfirstlane(t >> 6);  // wave id (uniform)
    int lane = t & 63;
    int ch0  = wv * 36;

    float acc[36];
#pragma unroll
    for (int j = 0; j < 36; j++) acc[j] = 0.f;

    const float* wt = wsc + O_WT;
    for (int c = 0; c < 256; c++) {
        float xv = xs[c * 64 + lane];
        const float* wr = wt + c * 144 + ch0;   // uniform address -> s_load
#pragma unroll
        for (int j = 0; j < 36; j++) acc[j] += xv * wr[j];
    }

    int pos = pos0 + lane;
#pragma unroll
    for (int j = 0; j < 36; j++) {
        int ch = ch0 + j;
        float r = acc[j] + wsc[O_BIAS + ch];
        if (ch < 64) {
            ws[O_Q + ((size_t)(b * 64 + ch)) * N_ + pos] = r;
        } else if (ch < 80) {
            ws[O_KEYS + ((size_t)(b * 16 + (ch - 64))) * N_ + pos] = r;
        } else {
            int ov = ch - 80;
            ws[O_VALS + ((size_t)(b * 64 + ov)) * N_ + pos] = r;
            ws[O_VALT + ((size_t)b * N_ + pos) * 64 + ov]   = r;
        }
    }
}

// ---------------- K2: row softmax over keys ------------------------------
__global__ __launch_bounds__(256) void k_softmax(float* __restrict__ ws) {
    int row = blockIdx.x;   // b*16 + k
    const float* src = ws + O_KEYS + (size_t)row * N_;
    float*       dst = ws + O_SM   + (size_t)row * N_;
    int t = threadIdx.x;

    float4 r[4];
#pragma unroll
    for (int i = 0; i < 4; i++) r[i] = *(const float4*)(src + i * 1024 + t * 4);

    float m = r[0].x;
#pragma unroll
    for (int i = 0; i < 4; i++) {
        m = fmaxf(m, r[i].x); m = fmaxf(m, r[i].y);
        m = fmaxf(m, r[i].z); m = fmaxf(m, r[i].w);
    }
    for (int off = 32; off > 0; off >>= 1) m = fmaxf(m, __shfl_xor(m, off));
    __shared__ float redm[4];
    if ((t & 63) == 0) redm[t >> 6] = m;
    __syncthreads();
    m = fmaxf(fmaxf(redm[0], redm[1]), fmaxf(redm[2], redm[3]));

    float s = 0.f;
#pragma unroll
    for (int i = 0; i < 4; i++) {
        r[i].x = expf(r[i].x - m); r[i].y = expf(r[i].y - m);
        r[i].z = expf(r[i].z - m); r[i].w = expf(r[i].w - m);
        s += r[i].x + r[i].y + r[i].z + r[i].w;
    }
    for (int off = 32; off > 0; off >>= 1) s += __shfl_xor(s, off);
    __shared__ float reds[4];
    if ((t & 63) == 0) reds[t >> 6] = s;
    __syncthreads();
    s = reds[0] + reds[1] + reds[2] + reds[3];
    float inv = 1.f / s;
#pragma unroll
    for (int i = 0; i < 4; i++) {
        float4 o = r[i];
        o.x *= inv; o.y *= inv; o.z *= inv; o.w *= inv;
        *(float4*)(dst + i * 1024 + t * 4) = o;
    }
}

// ---------------- K3: lam_c partials --------------------------------------
__global__ __launch_bounds__(256) void k_lamc(float* __restrict__ ws) {
    int b  = blockIdx.x >> 4;
    int ch = blockIdx.x & 15;     // n-chunk
    int n0 = ch * 256;
    __shared__ float sms[16 * 256];
    int t = threadIdx.x;
    for (int i = 0; i < 16; i++) {
        int idx = t + i * 256;
        int k = idx >> 8, n = idx & 255;
        sms[idx] = ws[O_SM + ((size_t)(b * 16 + k)) * N_ + n0 + n];
    }
    __syncthreads();

    int v  = t & 63;
    int kg = __builtin_amdgcn_readfirstlane(t >> 6);
    float acc[4] = {0.f, 0.f, 0.f, 0.f};
    const float* vt = ws + O_VALT + ((size_t)b * N_ + n0) * 64 + v;
    for (int n = 0; n < 256; n++) {
        float val = vt[(size_t)n * 64];
#pragma unroll
        for (int j = 0; j < 4; j++) acc[j] += sms[(kg * 4 + j) * 256 + n] * val;
    }
#pragma unroll
    for (int j = 0; j < 4; j++)
        ws[O_LCP + ((size_t)(b * 16 + ch) * 16 + kg * 4 + j) * 64 + v] = acc[j];
}

// ---------------- K4: reduce lam_c partials -------------------------------
__global__ void k_lcred(float* __restrict__ ws) {
    int b = blockIdx.x, t = threadIdx.x;   // 1024 threads = 16k x 64v
    float s = 0.f;
    for (int c = 0; c < 16; c++)
        s += ws[O_LCP + ((size_t)(b * 16 + c)) * 1024 + t];
    ws[O_LC + (size_t)b * 1024 + t] = s;
}

// ---------------- K5: fused conv(lam_p) + y_p + y_c ------------------------
__global__ __launch_bounds__(256, 2) void k_out(const float* __restrict__ wsc,
                                                float* __restrict__ out) {
    __shared__ float vals[16][756];   // [v][18*42] halo tile
    __shared__ float lc[16][16];      // lam_c[k][vi]
    int tile = blockIdx.x, vc = blockIdx.y, b = blockIdx.z;
    int x0 = (tile & 1) * 32, y0 = (tile >> 1) * 8;
    int v0 = vc * 16;
    int t  = threadIdx.x;

    {   // stage lam_c chunk
        int k = t >> 4, vi = t & 15;
        lc[k][vi] = wsc[O_LC + ((size_t)(b * 16 + k)) * 64 + v0 + vi];
    }
    // stage halo of values: rows [y0-5, y0+13), cols [x0-5, x0+37)
    const float* vsrc = wsc + O_VALS + (size_t)b * 64 * N_;
    for (int idx = t; idx < 16 * 756; idx += 256) {
        int v = idx / 756, rem = idx % 756;
        int hy = rem / 42, hx = rem % 42;
        int gy = y0 - 5 + hy, gx = x0 - 5 + hx;
        float val = 0.f;
        if ((unsigned)gy < 64u && (unsigned)gx < 64u)
            val = vsrc[(size_t)(v0 + v) * N_ + gy * 64 + gx];
        vals[v][hy * 42 + hx] = val;
    }

    int lx = t & 31, ly = t >> 5;
    int X = x0 + lx, Y = y0 + ly;
    int pos = Y * 64 + X;

    // q[h][k] in registers
    float q[4][16];
    const float* qsrc = wsc + O_Q + (size_t)b * 64 * N_ + pos;
#pragma unroll
    for (int h = 0; h < 4; h++)
#pragma unroll
        for (int k = 0; k < 16; k++)
            q[h][k] = qsrc[(size_t)(h * 16 + k) * N_];

    __syncthreads();

    float acc[4][16];
#pragma unroll
    for (int h = 0; h < 4; h++)
#pragma unroll
        for (int v = 0; v < 16; v++) acc[h][v] = 0.f;

    const float* embT = wsc + O_EMBT;
    for (int dy = 0; dy < 11; dy++) {
        // G[h][dx] = sum_k q[h][k] * emb[k][dy][dx]
        float G[4][11];
#pragma unroll
        for (int h = 0; h < 4; h++)
#pragma unroll
            for (int dx = 0; dx < 11; dx++) G[h][dx] = 0.f;
        const float* et = embT + dy * 11 * 16;   // uniform -> scalar loads
#pragma unroll
        for (int dx = 0; dx < 11; dx++) {
#pragma unroll
            for (int k = 0; k < 16; k++) {
                float e = et[dx * 16 + k];
#pragma unroll
                for (int h = 0; h < 4; h++) G[h][dx] += q[h][k] * e;
            }
        }
        const float* vrow = &vals[0][(ly + dy) * 42 + lx];
#pragma unroll
        for (int v = 0; v < 16; v++) {
#pragma unroll
            for (int dx = 0; dx < 11; dx++) {
                float val = vrow[v * 756 + dx];
#pragma unroll
                for (int h = 0; h < 4; h++) acc[h][v] += G[h][dx] * val;
            }
        }
    }

    // + y_c: acc[h][v] += sum_k q[h][k] * lam_c[k][v]
#pragma unroll
    for (int v = 0; v < 16; v++) {
#pragma unroll
        for (int k = 0; k < 16; k++) {
            float lcv = lc[k][v];
#pragma unroll
            for (int h = 0; h < 4; h++) acc[h][v] += q[h][k] * lcv;
        }
    }

#pragma unroll
    for (int h = 0; h < 4; h++)
#pragma unroll
        for (int v = 0; v < 16; v++)
            out[((size_t)(b * 256 + h * 64 + v0 + v)) * N_ + pos] = acc[h][v];
}

extern "C" void kernel_launch(void* const* d_in, const int* in_sizes, int n_in,
                              void* d_out, int out_size, void* d_ws, size_t ws_size,
                              hipStream_t stream) {
    const float* x   = (const float*)d_in[0];
    const float* Wq  = (const float*)d_in[1];
    const float* qg  = (const float*)d_in[2];
    const float* qb  = (const float*)d_in[3];
    const float* qm  = (const float*)d_in[4];
    const float* qv  = (const float*)d_in[5];
    const float* Wk  = (const float*)d_in[6];
    const float* Wv  = (const float*)d_in[7];
    const float* vg  = (const float*)d_in[8];
    const float* vb  = (const float*)d_in[9];
    const float* vm  = (const float*)d_in[10];
    const float* vva = (const float*)d_in[11];
    const float* emb = (const float*)d_in[12];
    float* ws  = (float*)d_ws;
    float* out = (float*)d_out;

    k_prep<<<1, 256, 0, stream>>>(Wq, qg, qb, qm, qv, Wk, Wv, vg, vb, vm, vva, emb, ws);
    k_proj<<<512, 256, 0, stream>>>(x, ws, ws);
    k_softmax<<<128, 256, 0, stream>>>(ws);
    k_lamc<<<128, 256, 0, stream>>>(ws);
    k_lcred<<<8, 1024, 0, stream>>>(ws);
    k_out<<<dim3(16, 4, 8), 256, 0, stream>>>(ws, out);
}

// Round 2
// 221.586 us; speedup vs baseline: 1.0148x; 1.0148x over previous
//
#include <hip/hip_runtime.h>
#include <math.h>

#define EPSBN 1e-5f

constexpr int B_ = 8, C_ = 256, N_ = 4096, IMG_ = 64;
constexpr int HEADS_ = 4, K_ = 16, VV_ = 64, M_ = 11, OC_ = 144;

// workspace layout (float offsets)
constexpr size_t O_WT   = 0;                                   // WcatT[256][144]
constexpr size_t O_BIAS = 36864;                               // [144]
constexpr size_t O_EMBT = 37120;                               // embT[121][16]
constexpr size_t O_Q    = 39424;                               // [8][64][4096]
constexpr size_t O_KEYS = O_Q    + (size_t)B_ * 64 * N_;       // [8][16][4096]
constexpr size_t O_SM   = O_KEYS + (size_t)B_ * 16 * N_;       // [8][16][4096]
constexpr size_t O_VALS = O_SM   + (size_t)B_ * 16 * N_;       // [8][64][4096]
constexpr size_t O_VALT = O_VALS + (size_t)B_ * 64 * N_;       // [8][4096][64]
constexpr size_t O_LCP  = O_VALT + (size_t)B_ * (size_t)N_ * 64; // [8][16][16][64]
constexpr size_t O_LC   = O_LCP  + (size_t)B_ * 16 * 16 * 64;  // [8][16][64]

// ---------------- K0: fold BN into weights, transpose emb ----------------
__global__ void k_prep(const float* __restrict__ Wq,
                       const float* __restrict__ qg, const float* __restrict__ qb,
                       const float* __restrict__ qm, const float* __restrict__ qv,
                       const float* __restrict__ Wk, const float* __restrict__ Wv,
                       const float* __restrict__ vg, const float* __restrict__ vb,
                       const float* __restrict__ vm, const float* __restrict__ vva,
                       const float* __restrict__ emb, float* __restrict__ ws) {
    int t = threadIdx.x, blk = blockIdx.x;
    int base = blk * 2304;                       // 16 blocks x 2304 = 36864
#pragma unroll
    for (int i = 0; i < 9; i++) {
        int idx = base + i * 256 + t;
        int c = idx / 144, o = idx % 144;
        float w;
        if (o < 64) {
            float s = qg[o] * rsqrtf(qv[o] + EPSBN);
            w = Wq[o * 256 + c] * s;
        } else if (o < 80) {
            w = Wk[(o - 64) * 256 + c];
        } else {
            int ov = o - 80;
            float s = vg[ov] * rsqrtf(vva[ov] + EPSBN);
            w = Wv[ov * 256 + c] * s;
        }
        ws[O_WT + idx] = w;
    }
    if (blk == 0 && t < 144) {
        float bias;
        if (t < 64) {
            float s = qg[t] * rsqrtf(qv[t] + EPSBN);
            bias = qb[t] - qm[t] * s;
        } else if (t < 80) {
            bias = 0.f;
        } else {
            int ov = t - 80;
            float s = vg[ov] * rsqrtf(vva[ov] + EPSBN);
            bias = vb[ov] - vm[ov] * s;
        }
        ws[O_BIAS + t] = bias;
    }
    if (blk == 15) {
        for (int idx = t; idx < 121 * 16; idx += 256) {
            int tap = idx >> 4, k = idx & 15;
            ws[O_EMBT + idx] = emb[k * 121 + tap];
        }
    }
}

// ---------------- K1: fused q/k/v projection (GEMM 144x256 x 256xN) ------
__global__ __launch_bounds__(256) void k_proj(const float* __restrict__ x,
                                              const float* __restrict__ wsc,
                                              float* __restrict__ ws) {
    __shared__ float xs[256 * 64];   // x[c][pos] tile, 64KB
    int b    = blockIdx.x >> 6;
    int pos0 = (blockIdx.x & 63) * 64;
    int t    = threadIdx.x;

    for (int i = 0; i < 16; i++) {
        int f4 = t + i * 256;            // 4096 float4s
        int c  = f4 >> 4, p4 = f4 & 15;
        float4 v = *(const float4*)(x + ((size_t)(b * 256 + c)) * N_ + pos0 + p4 * 4);
        *(float4*)(xs + c * 64 + p4 * 4) = v;
    }
    __syncthreads();

    int wv   = __builtin_amdgcn_readfirstlane(t >> 6);  // wave id (uniform)
    int lane = t & 63;
    int ch0  = wv * 36;

    float acc[36];
#pragma unroll
    for (int j = 0; j < 36; j++) acc[j] = 0.f;

    const float* wt = wsc + O_WT;
    for (int c = 0; c < 256; c++) {
        float xv = xs[c * 64 + lane];
        const float* wr = wt + c * 144 + ch0;   // uniform address -> s_load
#pragma unroll
        for (int j = 0; j < 36; j++) acc[j] += xv * wr[j];
    }

    int pos = pos0 + lane;
#pragma unroll
    for (int j = 0; j < 36; j++) {
        int ch = ch0 + j;
        float r = acc[j] + wsc[O_BIAS + ch];
        if (ch < 64) {
            ws[O_Q + ((size_t)(b * 64 + ch)) * N_ + pos] = r;
        } else if (ch < 80) {
            ws[O_KEYS + ((size_t)(b * 16 + (ch - 64))) * N_ + pos] = r;
        } else {
            int ov = ch - 80;
            ws[O_VALS + ((size_t)(b * 64 + ov)) * N_ + pos] = r;
            ws[O_VALT + ((size_t)b * N_ + pos) * 64 + ov]   = r;
        }
    }
}

// ---------------- K2: row softmax over keys ------------------------------
__global__ __launch_bounds__(1024) void k_softmax(float* __restrict__ ws) {
    int row = blockIdx.x;   // b*16 + k
    const float* src = ws + O_KEYS + (size_t)row * N_;
    float*       dst = ws + O_SM   + (size_t)row * N_;
    int t = threadIdx.x;

    float4 r = *(const float4*)(src + t * 4);

    float m = fmaxf(fmaxf(r.x, r.y), fmaxf(r.z, r.w));
    for (int off = 32; off > 0; off >>= 1) m = fmaxf(m, __shfl_xor(m, off));
    __shared__ float redm[16];
    __shared__ float reds[16];
    if ((t & 63) == 0) redm[t >> 6] = m;
    __syncthreads();
    m = redm[0];
#pragma unroll
    for (int i = 1; i < 16; i++) m = fmaxf(m, redm[i]);

    r.x = expf(r.x - m); r.y = expf(r.y - m);
    r.z = expf(r.z - m); r.w = expf(r.w - m);
    float s = r.x + r.y + r.z + r.w;
    for (int off = 32; off > 0; off >>= 1) s += __shfl_xor(s, off);
    if ((t & 63) == 0) reds[t >> 6] = s;
    __syncthreads();
    s = reds[0];
#pragma unroll
    for (int i = 1; i < 16; i++) s += reds[i];
    float inv = 1.f / s;
    r.x *= inv; r.y *= inv; r.z *= inv; r.w *= inv;
    *(float4*)(dst + t * 4) = r;
}

// ---------------- K3: lam_c partials --------------------------------------
__global__ __launch_bounds__(256) void k_lamc(float* __restrict__ ws) {
    int b  = blockIdx.x >> 4;
    int ch = blockIdx.x & 15;     // n-chunk
    int n0 = ch * 256;
    __shared__ float sms[16 * 256];
    int t = threadIdx.x;
    for (int i = 0; i < 16; i++) {
        int idx = t + i * 256;
        int k = idx >> 8, n = idx & 255;
        sms[idx] = ws[O_SM + ((size_t)(b * 16 + k)) * N_ + n0 + n];
    }
    __syncthreads();

    int v  = t & 63;
    int kg = __builtin_amdgcn_readfirstlane(t >> 6);
    float acc[4] = {0.f, 0.f, 0.f, 0.f};
    const float* vt = ws + O_VALT + ((size_t)b * N_ + n0) * 64 + v;
    for (int n = 0; n < 256; n++) {
        float val = vt[(size_t)n * 64];
#pragma unroll
        for (int j = 0; j < 4; j++) acc[j] += sms[(kg * 4 + j) * 256 + n] * val;
    }
#pragma unroll
    for (int j = 0; j < 4; j++)
        ws[O_LCP + ((size_t)(b * 16 + ch) * 16 + kg * 4 + j) * 64 + v] = acc[j];
}

// ---------------- K4: reduce lam_c partials -------------------------------
__global__ void k_lcred(float* __restrict__ ws) {
    int b = blockIdx.x, t = threadIdx.x;   // 1024 threads = 16k x 64v
    float s = 0.f;
    for (int c = 0; c < 16; c++)
        s += ws[O_LCP + ((size_t)(b * 16 + c)) * 1024 + t];
    ws[O_LC + (size_t)b * 1024 + t] = s;
}

// ---------------- K5: fused conv(lam_p) + y_p + y_c ------------------------
// h split across blocks: each block does 2 heads x 16 v for a 32x8 tile.
// Register budget: q[2][16]=32 + acc[2][16]=32 + G[2][11]=22 ~ 86 live.
__global__ __launch_bounds__(256, 3) void k_out(const float* __restrict__ wsc,
                                                float* __restrict__ out) {
    __shared__ float vals[16][756];   // [v][18*42] halo tile (48.4KB)
    __shared__ float lc[16][16];      // lam_c[k][vi]
    int tile = blockIdx.x, yz = blockIdx.y, b = blockIdx.z;
    int vc = yz & 3, hp = yz >> 2;
    int x0 = (tile & 1) * 32, y0 = (tile >> 1) * 8;
    int v0 = vc * 16, h0 = hp * 2;
    int t  = threadIdx.x;

    {   // stage lam_c chunk
        int k = t >> 4, vi = t & 15;
        lc[k][vi] = wsc[O_LC + ((size_t)(b * 16 + k)) * 64 + v0 + vi];
    }
    // stage halo of values: rows [y0-5, y0+13), cols [x0-5, x0+37)
    const float* vsrc = wsc + O_VALS + (size_t)b * 64 * N_;
    for (int idx = t; idx < 16 * 756; idx += 256) {
        int v = idx / 756, rem = idx % 756;
        int hy = rem / 42, hx = rem % 42;
        int gy = y0 - 5 + hy, gx = x0 - 5 + hx;
        float val = 0.f;
        if ((unsigned)gy < 64u && (unsigned)gx < 64u)
            val = vsrc[(size_t)(v0 + v) * N_ + gy * 64 + gx];
        vals[v][hy * 42 + hx] = val;
    }

    int lx = t & 31, ly = t >> 5;
    int X = x0 + lx, Y = y0 + ly;
    int pos = Y * 64 + X;

    // q[h][k] for this block's 2 heads, in registers
    float q[2][16];
    const float* qsrc = wsc + O_Q + (size_t)b * 64 * N_ + (size_t)h0 * 16 * N_ + pos;
#pragma unroll
    for (int h = 0; h < 2; h++)
#pragma unroll
        for (int k = 0; k < 16; k++)
            q[h][k] = qsrc[(size_t)(h * 16 + k) * N_];

    __syncthreads();

    float acc[2][16];
#pragma unroll
    for (int h = 0; h < 2; h++)
#pragma unroll
        for (int v = 0; v < 16; v++) acc[h][v] = 0.f;

    const float* embT = wsc + O_EMBT;
    for (int dy = 0; dy < 11; dy++) {
        // G[h][dx] = sum_k q[h][k] * emb[k][dy][dx]
        float G[2][11];
#pragma unroll
        for (int h = 0; h < 2; h++)
#pragma unroll
            for (int dx = 0; dx < 11; dx++) G[h][dx] = 0.f;
        const float* et = embT + dy * 11 * 16 + h0;  // uniform -> scalar loads
#pragma unroll
        for (int dx = 0; dx < 11; dx++) {
#pragma unroll
            for (int k = 0; k < 16; k++) {
                float e = embT[dy * 176 + dx * 16 + k];
#pragma unroll
                for (int h = 0; h < 2; h++) G[h][dx] += q[h][k] * e;
            }
        }
        (void)et;
        const float* vrow = &vals[0][(ly + dy) * 42 + lx];
#pragma unroll
        for (int v = 0; v < 16; v++) {
#pragma unroll
            for (int dx = 0; dx < 11; dx++) {
                float val = vrow[v * 756 + dx];
#pragma unroll
                for (int h = 0; h < 2; h++) acc[h][v] += G[h][dx] * val;
            }
        }
    }

    // + y_c: acc[h][v] += sum_k q[h][k] * lam_c[k][v]
#pragma unroll
    for (int v = 0; v < 16; v++) {
#pragma unroll
        for (int k = 0; k < 16; k++) {
            float lcv = lc[k][v];
#pragma unroll
            for (int h = 0; h < 2; h++) acc[h][v] += q[h][k] * lcv;
        }
    }

#pragma unroll
    for (int h = 0; h < 2; h++)
#pragma unroll
        for (int v = 0; v < 16; v++)
            out[((size_t)(b * 256 + (h0 + h) * 64 + v0 + v)) * N_ + pos] = acc[h][v];
}

extern "C" void kernel_launch(void* const* d_in, const int* in_sizes, int n_in,
                              void* d_out, int out_size, void* d_ws, size_t ws_size,
                              hipStream_t stream) {
    const float* x   = (const float*)d_in[0];
    const float* Wq  = (const float*)d_in[1];
    const float* qg  = (const float*)d_in[2];
    const float* qb  = (const float*)d_in[3];
    const float* qm  = (const float*)d_in[4];
    const float* qv  = (const float*)d_in[5];
    const float* Wk  = (const float*)d_in[6];
    const float* Wv  = (const float*)d_in[7];
    const float* vg  = (const float*)d_in[8];
    const float* vb  = (const float*)d_in[9];
    const float* vm  = (const float*)d_in[10];
    const float* vva = (const float*)d_in[11];
    const float* emb = (const float*)d_in[12];
    float* ws  = (float*)d_ws;
    float* out = (float*)d_out;

    k_prep<<<16, 256, 0, stream>>>(Wq, qg, qb, qm, qv, Wk, Wv, vg, vb, vm, vva, emb, ws);
    k_proj<<<512, 256, 0, stream>>>(x, ws, ws);
    k_softmax<<<128, 1024, 0, stream>>>(ws);
    k_lamc<<<128, 256, 0, stream>>>(ws);
    k_lcred<<<8, 1024, 0, stream>>>(ws);
    k_out<<<dim3(16, 8, 8), 256, 0, stream>>>(ws, out);
}

// Round 3
// 136.820 us; speedup vs baseline: 1.6434x; 1.6195x over previous
//
#include <hip/hip_runtime.h>
#include <math.h>

#define EPSBN 1e-5f

constexpr int B_ = 8, C_ = 256, N_ = 4096, IMG_ = 64;
constexpr int HEADS_ = 4, K_ = 16, VV_ = 64, M_ = 11, OC_ = 144;

typedef _Float16 half4 __attribute__((ext_vector_type(4)));
typedef float f32x4 __attribute__((ext_vector_type(4)));

// workspace layout (float offsets)
constexpr size_t O_WT   = 0;                                   // WcatT[256][144]
constexpr size_t O_BIAS = 36864;                               // [144]
constexpr size_t O_EMBT = 37120;                               // embF16[11][16][16] (f16) in 2304-float slot
constexpr size_t O_Q    = 39424;                               // [8][64][4096]
constexpr size_t O_KEYS = O_Q    + (size_t)B_ * 64 * N_;       // [8][16][4096]
constexpr size_t O_SM   = O_KEYS + (size_t)B_ * 16 * N_;       // [8][16][4096]
constexpr size_t O_VALS = O_SM   + (size_t)B_ * 16 * N_;       // [8][64][4096]
constexpr size_t O_VALT = O_VALS + (size_t)B_ * 64 * N_;       // [8][4096][64]
constexpr size_t O_LCP  = O_VALT + (size_t)B_ * (size_t)N_ * 64; // [8][16][16][64]
constexpr size_t O_LC   = O_LCP  + (size_t)B_ * 16 * 16 * 64;  // [8][16][64]

// ---------------- K0: fold BN into weights, build f16 emb table ----------
__global__ void k_prep(const float* __restrict__ Wq,
                       const float* __restrict__ qg, const float* __restrict__ qb,
                       const float* __restrict__ qm, const float* __restrict__ qv,
                       const float* __restrict__ Wk, const float* __restrict__ Wv,
                       const float* __restrict__ vg, const float* __restrict__ vb,
                       const float* __restrict__ vm, const float* __restrict__ vva,
                       const float* __restrict__ emb, float* __restrict__ ws) {
    int t = threadIdx.x, blk = blockIdx.x;
    int base = blk * 2304;                       // 16 blocks x 2304 = 36864
#pragma unroll
    for (int i = 0; i < 9; i++) {
        int idx = base + i * 256 + t;
        int c = idx / 144, o = idx % 144;
        float w;
        if (o < 64) {
            float s = qg[o] * rsqrtf(qv[o] + EPSBN);
            w = Wq[o * 256 + c] * s;
        } else if (o < 80) {
            w = Wk[(o - 64) * 256 + c];
        } else {
            int ov = o - 80;
            float s = vg[ov] * rsqrtf(vva[ov] + EPSBN);
            w = Wv[ov * 256 + c] * s;
        }
        ws[O_WT + idx] = w;
    }
    if (blk == 0 && t < 144) {
        float bias;
        if (t < 64) {
            float s = qg[t] * rsqrtf(qv[t] + EPSBN);
            bias = qb[t] - qm[t] * s;
        } else if (t < 80) {
            bias = 0.f;
        } else {
            int ov = t - 80;
            float s = vg[ov] * rsqrtf(vva[ov] + EPSBN);
            bias = vb[ov] - vm[ov] * s;
        }
        ws[O_BIAS + t] = bias;
    }
    if (blk == 15) {
        // embF16[dy][dx(16, zero-pad >=11)][k(16)] = emb[k][dy][dx]
        _Float16* ef = (_Float16*)(ws + O_EMBT);
        for (int idx = t; idx < 11 * 16 * 16; idx += 256) {
            int dy = idx >> 8, dx = (idx >> 4) & 15, k = idx & 15;
            float v = (dx < 11) ? emb[k * 121 + dy * 11 + dx] : 0.f;
            ef[idx] = (_Float16)v;
        }
    }
}

// ---------------- K1: fused q/k/v projection (GEMM 144x256 x 256xN) ------
__global__ __launch_bounds__(256) void k_proj(const float* __restrict__ x,
                                              const float* __restrict__ wsc,
                                              float* __restrict__ ws) {
    __shared__ float xs[256 * 64];   // x[c][pos] tile, 64KB
    int b    = blockIdx.x >> 6;
    int pos0 = (blockIdx.x & 63) * 64;
    int t    = threadIdx.x;

    for (int i = 0; i < 16; i++) {
        int f4 = t + i * 256;            // 4096 float4s
        int c  = f4 >> 4, p4 = f4 & 15;
        float4 v = *(const float4*)(x + ((size_t)(b * 256 + c)) * N_ + pos0 + p4 * 4);
        *(float4*)(xs + c * 64 + p4 * 4) = v;
    }
    __syncthreads();

    int wv   = __builtin_amdgcn_readfirstlane(t >> 6);  // wave id (uniform)
    int lane = t & 63;
    int ch0  = wv * 36;

    float acc[36];
#pragma unroll
    for (int j = 0; j < 36; j++) acc[j] = 0.f;

    const float* wt = wsc + O_WT;
    for (int c = 0; c < 256; c++) {
        float xv = xs[c * 64 + lane];
        const float* wr = wt + c * 144 + ch0;   // uniform address -> s_load
#pragma unroll
        for (int j = 0; j < 36; j++) acc[j] += xv * wr[j];
    }

    int pos = pos0 + lane;
#pragma unroll
    for (int j = 0; j < 36; j++) {
        int ch = ch0 + j;
        float r = acc[j] + wsc[O_BIAS + ch];
        if (ch < 64) {
            ws[O_Q + ((size_t)(b * 64 + ch)) * N_ + pos] = r;
        } else if (ch < 80) {
            ws[O_KEYS + ((size_t)(b * 16 + (ch - 64))) * N_ + pos] = r;
        } else {
            int ov = ch - 80;
            ws[O_VALS + ((size_t)(b * 64 + ov)) * N_ + pos] = r;
            ws[O_VALT + ((size_t)b * N_ + pos) * 64 + ov]   = r;
        }
    }
}

// ---------------- K2: row softmax over keys ------------------------------
__global__ __launch_bounds__(1024) void k_softmax(float* __restrict__ ws) {
    int row = blockIdx.x;   // b*16 + k
    const float* src = ws + O_KEYS + (size_t)row * N_;
    float*       dst = ws + O_SM   + (size_t)row * N_;
    int t = threadIdx.x;

    float4 r = *(const float4*)(src + t * 4);

    float m = fmaxf(fmaxf(r.x, r.y), fmaxf(r.z, r.w));
    for (int off = 32; off > 0; off >>= 1) m = fmaxf(m, __shfl_xor(m, off));
    __shared__ float redm[16];
    __shared__ float reds[16];
    if ((t & 63) == 0) redm[t >> 6] = m;
    __syncthreads();
    m = redm[0];
#pragma unroll
    for (int i = 1; i < 16; i++) m = fmaxf(m, redm[i]);

    r.x = expf(r.x - m); r.y = expf(r.y - m);
    r.z = expf(r.z - m); r.w = expf(r.w - m);
    float s = r.x + r.y + r.z + r.w;
    for (int off = 32; off > 0; off >>= 1) s += __shfl_xor(s, off);
    if ((t & 63) == 0) reds[t >> 6] = s;
    __syncthreads();
    s = reds[0];
#pragma unroll
    for (int i = 1; i < 16; i++) s += reds[i];
    float inv = 1.f / s;
    r.x *= inv; r.y *= inv; r.z *= inv; r.w *= inv;
    *(float4*)(dst + t * 4) = r;
}

// ---------------- K3: lam_c partials --------------------------------------
__global__ __launch_bounds__(256) void k_lamc(float* __restrict__ ws) {
    int b  = blockIdx.x >> 4;
    int ch = blockIdx.x & 15;     // n-chunk
    int n0 = ch * 256;
    __shared__ float sms[16 * 256];
    int t = threadIdx.x;
    for (int i = 0; i < 16; i++) {
        int idx = t + i * 256;
        int k = idx >> 8, n = idx & 255;
        sms[idx] = ws[O_SM + ((size_t)(b * 16 + k)) * N_ + n0 + n];
    }
    __syncthreads();

    int v  = t & 63;
    int kg = __builtin_amdgcn_readfirstlane(t >> 6);
    float acc[4] = {0.f, 0.f, 0.f, 0.f};
    const float* vt = ws + O_VALT + ((size_t)b * N_ + n0) * 64 + v;
    for (int n = 0; n < 256; n++) {
        float val = vt[(size_t)n * 64];
#pragma unroll
        for (int j = 0; j < 4; j++) acc[j] += sms[(kg * 4 + j) * 256 + n] * val;
    }
#pragma unroll
    for (int j = 0; j < 4; j++)
        ws[O_LCP + ((size_t)(b * 16 + ch) * 16 + kg * 4 + j) * 64 + v] = acc[j];
}

// ---------------- K4: reduce lam_c partials -------------------------------
__global__ void k_lcred(float* __restrict__ ws) {
    int b = blockIdx.x, t = threadIdx.x;   // 1024 threads = 16k x 64v
    float s = 0.f;
    for (int c = 0; c < 16; c++)
        s += ws[O_LCP + ((size_t)(b * 16 + c)) * 1024 + t];
    ws[O_LC + (size_t)b * 1024 + t] = s;
}

// ---------------- K5: MFMA conv + y_p + y_c -------------------------------
// lam_p[k, x-tile] per (v,row,dy) via v_mfma_f32_16x16x16f16:
//   A[m=k_lam][kk=dx] = embF16[dy][dx][k_lam]   (wave-shared frags, preloaded)
//   B[kk=dx][n=x]     = val_f16[v][row+dy][x + dx - 5]  (im2col from LDS)
//   D[m][n]: lane holds k_lam = 4*(l>>4)+i, x = x0 + (l&15)
// Epilogue per lane: y[h] = sum_i q[h][4g+i]*(lamD[i]+lam_c), butterfly over
// lane^16/^32, lane-group g stores head h=g.
// Dual LDS copies (normal & shifted-by-1) make the 4-elem B window two
// aligned ds_read_b32 for any lane.
__global__ __launch_bounds__(256, 4) void k_out(const float* __restrict__ wsc,
                                                float* __restrict__ out) {
    __shared__ _Float16 vt[2][4][18][88];   // 25344 B
    int ytile = blockIdx.x;                 // 0..7  (8 rows each)
    int vc    = blockIdx.y;                 // 0..15 (4 v each)
    int b     = blockIdx.z;
    int y0 = ytile * 8, v0 = vc * 4;
    int t = threadIdx.x;
    int w = t >> 6, l = t & 63;
    int g = l >> 4, nb = l & 15;

    // ---- stage value tile as f16, two copies (copy1 shifted left by 1) ----
    const float* vsrc = wsc + O_VALS + (size_t)b * 64 * N_;
    for (int idx = t; idx < 2 * 4 * 18 * 88; idx += 256) {
        int cp = idx / 6336, rem = idx % 6336;
        int v = rem / 1584, rem2 = rem % 1584;
        int r = rem2 / 88, c = rem2 % 88;
        int gy = y0 - 5 + r, gx = c - 8 + cp;
        _Float16 h = (_Float16)0.f;
        if ((unsigned)gy < 64u && (unsigned)gx < 64u)
            h = (_Float16)vsrc[(size_t)(v0 + v) * N_ + gy * 64 + gx];
        vt[cp][v][r][c] = h;
    }

    // ---- preload the 11 A-fragments (emb) --------------------------------
    half4 af[11];
    const _Float16* ef = (const _Float16*)(wsc + O_EMBT);
#pragma unroll
    for (int dy = 0; dy < 11; dy++) {
#pragma unroll
        for (int i = 0; i < 4; i++)
            af[dy][i] = ef[(dy * 16 + 4 * g + i) * 16 + nb];
    }

    __syncthreads();

    const char* ldsB = (const char*)&vt[0][0][0][0];

    for (int yy2 = 0; yy2 < 2; yy2++) {
        int yy = w * 2 + yy2;               // output row within tile (0..7)
        for (int xt = 0; xt < 4; xt++) {
            int pos = (y0 + yy) * 64 + xt * 16 + nb;
            // q[h][i] for this lane's 4 k-slices
            float q4[4][4];
            const float* qsrc = wsc + O_Q + (size_t)b * 64 * N_ + pos;
#pragma unroll
            for (int h = 0; h < 4; h++)
#pragma unroll
                for (int i = 0; i < 4; i++)
                    q4[h][i] = qsrc[(size_t)(h * 16 + 4 * g + i) * N_];

            int base = xt * 16 + nb + 4 * g + 3;    // window start (array col)
            int cp = base & 1, ub = base & ~1;

            for (int vp = 0; vp < 2; vp++) {
                int vA = vp * 2, vB = vp * 2 + 1;
                f32x4 dA = {0.f, 0.f, 0.f, 0.f}, dB = {0.f, 0.f, 0.f, 0.f};
                const char* pA = ldsB + (size_t)cp * 12672 + ((vA * 18 + yy) * 88 + ub) * 2;
                const char* pB = ldsB + (size_t)cp * 12672 + ((vB * 18 + yy) * 88 + ub) * 2;
#pragma unroll
                for (int dy = 0; dy < 11; dy++) {
                    union { uint u[2]; half4 h; } bA, bB;
                    bA.u[0] = *(const uint*)(pA + dy * 176);
                    bA.u[1] = *(const uint*)(pA + dy * 176 + 4);
                    bB.u[0] = *(const uint*)(pB + dy * 176);
                    bB.u[1] = *(const uint*)(pB + dy * 176 + 4);
                    dA = __builtin_amdgcn_mfma_f32_16x16x16f16(af[dy], bA.h, dA, 0, 0, 0);
                    dB = __builtin_amdgcn_mfma_f32_16x16x16f16(af[dy], bB.h, dB, 0, 0, 0);
                }
                // + lam_c, then contract with q, butterfly-reduce over k-groups
#pragma unroll
                for (int vv = 0; vv < 2; vv++) {
                    f32x4 d = vv ? dB : dA;
                    int vidx = vp * 2 + vv;
                    float lc0, lc1, lc2, lc3;
                    {
                        const float* lcp = wsc + O_LC + ((size_t)(b * 16 + 4 * g)) * 64 + v0 + vidx;
                        lc0 = lcp[0]; lc1 = lcp[64]; lc2 = lcp[128]; lc3 = lcp[192];
                    }
                    float d0 = d[0] + lc0, d1 = d[1] + lc1, d2 = d[2] + lc2, d3 = d[3] + lc3;
                    float ph[4];
#pragma unroll
                    for (int h = 0; h < 4; h++) {
                        float p = q4[h][0] * d0 + q4[h][1] * d1 + q4[h][2] * d2 + q4[h][3] * d3;
                        p += __shfl_xor(p, 16);
                        p += __shfl_xor(p, 32);
                        ph[h] = p;
                    }
                    float o = (g == 0) ? ph[0] : (g == 1) ? ph[1] : (g == 2) ? ph[2] : ph[3];
                    out[((size_t)(b * 256 + g * 64 + v0 + vidx)) * N_ + pos] = o;
                }
            }
        }
    }
}

extern "C" void kernel_launch(void* const* d_in, const int* in_sizes, int n_in,
                              void* d_out, int out_size, void* d_ws, size_t ws_size,
                              hipStream_t stream) {
    const float* x   = (const float*)d_in[0];
    const float* Wq  = (const float*)d_in[1];
    const float* qg  = (const float*)d_in[2];
    const float* qb  = (const float*)d_in[3];
    const float* qm  = (const float*)d_in[4];
    const float* qv  = (const float*)d_in[5];
    const float* Wk  = (const float*)d_in[6];
    const float* Wv  = (const float*)d_in[7];
    const float* vg  = (const float*)d_in[8];
    const float* vb  = (const float*)d_in[9];
    const float* vm  = (const float*)d_in[10];
    const float* vva = (const float*)d_in[11];
    const float* emb = (const float*)d_in[12];
    float* ws  = (float*)d_ws;
    float* out = (float*)d_out;

    k_prep<<<16, 256, 0, stream>>>(Wq, qg, qb, qm, qv, Wk, Wv, vg, vb, vm, vva, emb, ws);
    k_proj<<<512, 256, 0, stream>>>(x, ws, ws);
    k_softmax<<<128, 1024, 0, stream>>>(ws);
    k_lamc<<<128, 256, 0, stream>>>(ws);
    k_lcred<<<8, 1024, 0, stream>>>(ws);
    k_out<<<dim3(8, 16, 8), 256, 0, stream>>>(ws, out);
}

// Round 4
// 92.235 us; speedup vs baseline: 2.4378x; 1.4834x over previous
//
#include <hip/hip_runtime.h>
#include <math.h>

#define EPSBN 1e-5f

constexpr int B_ = 8, C_ = 256, N_ = 4096, IMG_ = 64;
constexpr int HEADS_ = 4, K_ = 16, VV_ = 64, M_ = 11, OC_ = 144;

typedef _Float16 half4 __attribute__((ext_vector_type(4)));
typedef float f32x4 __attribute__((ext_vector_type(4)));

// workspace layout (float offsets)
constexpr size_t O_WT   = 0;                                   // Wf16[144][256] (f16, 18432 floats used)
constexpr size_t O_BIAS = 36864;                               // [144]
constexpr size_t O_EMBT = 37120;                               // embF16[11][16][16] (f16)
constexpr size_t O_Q    = 39424;                               // [8][64][4096]
constexpr size_t O_KEYS = O_Q    + (size_t)B_ * 64 * N_;       // [8][16][4096]
constexpr size_t O_SM   = O_KEYS + (size_t)B_ * 16 * N_;       // [8][16][4096]
constexpr size_t O_VALS = O_SM   + (size_t)B_ * 16 * N_;       // [8][64][4096]
constexpr size_t O_VALT = O_VALS + (size_t)B_ * 64 * N_;       // [8][4096][64]
constexpr size_t O_LCP  = O_VALT + (size_t)B_ * (size_t)N_ * 64; // [8][16][16][64]
constexpr size_t O_LC   = O_LCP  + (size_t)B_ * 16 * 16 * 64;  // [8][16][64]

// ---------------- K0: fold BN into f16 weights, build f16 emb table ------
__global__ void k_prep(const float* __restrict__ Wq,
                       const float* __restrict__ qg, const float* __restrict__ qb,
                       const float* __restrict__ qm, const float* __restrict__ qv,
                       const float* __restrict__ Wk, const float* __restrict__ Wv,
                       const float* __restrict__ vg, const float* __restrict__ vb,
                       const float* __restrict__ vm, const float* __restrict__ vva,
                       const float* __restrict__ emb, float* __restrict__ ws) {
    int t = threadIdx.x, blk = blockIdx.x;
    _Float16* wf = (_Float16*)(ws + O_WT);
    int base = blk * 2304;                       // 16 blocks x 2304 = 36864
#pragma unroll
    for (int i = 0; i < 9; i++) {
        int idx = base + i * 256 + t;
        int o = idx >> 8, c = idx & 255;         // Wf16[o][c]
        float w;
        if (o < 64) {
            float s = qg[o] * rsqrtf(qv[o] + EPSBN);
            w = Wq[o * 256 + c] * s;
        } else if (o < 80) {
            w = Wk[(o - 64) * 256 + c];
        } else {
            int ov = o - 80;
            float s = vg[ov] * rsqrtf(vva[ov] + EPSBN);
            w = Wv[ov * 256 + c] * s;
        }
        wf[idx] = (_Float16)w;
    }
    if (blk == 0 && t < 144) {
        float bias;
        if (t < 64) {
            float s = qg[t] * rsqrtf(qv[t] + EPSBN);
            bias = qb[t] - qm[t] * s;
        } else if (t < 80) {
            bias = 0.f;
        } else {
            int ov = t - 80;
            float s = vg[ov] * rsqrtf(vva[ov] + EPSBN);
            bias = vb[ov] - vm[ov] * s;
        }
        ws[O_BIAS + t] = bias;
    }
    if (blk == 15) {
        // embF16[dy][dx(16, zero-pad >=11)][k(16)] = emb[k][dy][dx]
        _Float16* ef = (_Float16*)(ws + O_EMBT);
        for (int idx = t; idx < 11 * 16 * 16; idx += 256) {
            int dy = idx >> 8, dx = (idx >> 4) & 15, k = idx & 15;
            float v = (dx < 11) ? emb[k * 121 + dy * 11 + dx] : 0.f;
            ef[idx] = (_Float16)v;
        }
    }
}

// ---------------- K1: MFMA q/k/v projection ------------------------------
// C[144, Ntile=128] = W[144,256] x X[256,128] via 16x16x16 f16 MFMA.
// LDS: W as [ch][c-pair uint] rows padded to 130 uints; x transposed
// [pos][c-pair uint] rows padded to 130 (pad => 2-way banks = free).
__global__ __launch_bounds__(256) void k_proj(const float* __restrict__ x,
                                              const float* __restrict__ wsc,
                                              float* __restrict__ ws) {
    __shared__ uint WL[144 * 130];   // 74880 B
    __shared__ uint XL[128 * 130];   // 66560 B
    int b    = blockIdx.y;
    int pos0 = blockIdx.x * 128;
    int t    = threadIdx.x;

    // stage W (144*128 uints, consecutive)
    const uint* wsrc = (const uint*)(wsc + O_WT);
#pragma unroll
    for (int i = 0; i < 72; i++) {
        int u = t + i * 256;
        int o = u >> 7, cu = u & 127;
        WL[o * 130 + cu] = wsrc[u];
    }
    // stage x transposed+f16: tasks = 128 c-pairs x 32 pos-quads
    const float* xb = x + (size_t)b * C_ * N_ + pos0;
#pragma unroll
    for (int i = 0; i < 16; i++) {
        int f = t + i * 256;
        int cp = f >> 5, p4 = f & 31;
        float4 a0 = *(const float4*)(xb + (size_t)(2 * cp) * N_ + 4 * p4);
        float4 a1 = *(const float4*)(xb + (size_t)(2 * cp + 1) * N_ + 4 * p4);
        union { _Float16 h[2]; uint u; } pk;
#pragma unroll
        for (int j = 0; j < 4; j++) {
            float v0 = (j == 0) ? a0.x : (j == 1) ? a0.y : (j == 2) ? a0.z : a0.w;
            float v1 = (j == 0) ? a1.x : (j == 1) ? a1.y : (j == 2) ? a1.z : a1.w;
            pk.h[0] = (_Float16)v0; pk.h[1] = (_Float16)v1;
            XL[(4 * p4 + j) * 130 + cp] = pk.u;
        }
    }
    __syncthreads();

    int w = t >> 6, l = t & 63;
    int g = l >> 4, r = l & 15;

    f32x4 acc[9][2];
#pragma unroll
    for (int mf = 0; mf < 9; mf++)
#pragma unroll
        for (int nf = 0; nf < 2; nf++) acc[mf][nf] = (f32x4){0.f, 0.f, 0.f, 0.f};

    union u2h { uint2 u; half4 h; };
    for (int ks = 0; ks < 16; ks++) {
        int cu = 8 * ks + 2 * g;
        u2h bf0, bf1;
        bf0.u = *(const uint2*)&XL[((2 * w + 0) * 16 + r) * 130 + cu];
        bf1.u = *(const uint2*)&XL[((2 * w + 1) * 16 + r) * 130 + cu];
#pragma unroll
        for (int mf = 0; mf < 9; mf++) {
            u2h af;
            af.u = *(const uint2*)&WL[(16 * mf + r) * 130 + cu];
            acc[mf][0] = __builtin_amdgcn_mfma_f32_16x16x16f16(af.h, bf0.h, acc[mf][0], 0, 0, 0);
            acc[mf][1] = __builtin_amdgcn_mfma_f32_16x16x16f16(af.h, bf1.h, acc[mf][1], 0, 0, 0);
        }
    }

    // epilogue: D[m=16mf+4g+reg][n=pos], add bias, route to q/keys/vals(+valT)
#pragma unroll
    for (int mf = 0; mf < 9; mf++) {
        float4 bias4 = *(const float4*)(wsc + O_BIAS + 16 * mf + 4 * g);
        int ch0 = 16 * mf + 4 * g;
#pragma unroll
        for (int nf = 0; nf < 2; nf++) {
            int pos = pos0 + (2 * w + nf) * 16 + r;
            f32x4 a = acc[mf][nf];
            float rv0 = a[0] + bias4.x, rv1 = a[1] + bias4.y;
            float rv2 = a[2] + bias4.z, rv3 = a[3] + bias4.w;
            if (mf < 4) {
                float* qp = ws + O_Q + ((size_t)(b * 64 + ch0)) * N_ + pos;
                qp[0] = rv0; qp[(size_t)N_] = rv1; qp[2 * (size_t)N_] = rv2; qp[3 * (size_t)N_] = rv3;
            } else if (mf == 4) {
                float* kp = ws + O_KEYS + ((size_t)(b * 16 + (ch0 - 64))) * N_ + pos;
                kp[0] = rv0; kp[(size_t)N_] = rv1; kp[2 * (size_t)N_] = rv2; kp[3 * (size_t)N_] = rv3;
            } else {
                int ov = ch0 - 80;
                float* vp = ws + O_VALS + ((size_t)(b * 64 + ov)) * N_ + pos;
                vp[0] = rv0; vp[(size_t)N_] = rv1; vp[2 * (size_t)N_] = rv2; vp[3 * (size_t)N_] = rv3;
                float4 v4 = make_float4(rv0, rv1, rv2, rv3);
                *(float4*)(ws + O_VALT + ((size_t)b * N_ + pos) * 64 + ov) = v4;
            }
        }
    }
}

// ---------------- K2: row softmax over keys ------------------------------
__global__ __launch_bounds__(1024) void k_softmax(float* __restrict__ ws) {
    int row = blockIdx.x;   // b*16 + k
    const float* src = ws + O_KEYS + (size_t)row * N_;
    float*       dst = ws + O_SM   + (size_t)row * N_;
    int t = threadIdx.x;

    float4 r = *(const float4*)(src + t * 4);

    float m = fmaxf(fmaxf(r.x, r.y), fmaxf(r.z, r.w));
    for (int off = 32; off > 0; off >>= 1) m = fmaxf(m, __shfl_xor(m, off));
    __shared__ float redm[16];
    __shared__ float reds[16];
    if ((t & 63) == 0) redm[t >> 6] = m;
    __syncthreads();
    m = redm[0];
#pragma unroll
    for (int i = 1; i < 16; i++) m = fmaxf(m, redm[i]);

    r.x = expf(r.x - m); r.y = expf(r.y - m);
    r.z = expf(r.z - m); r.w = expf(r.w - m);
    float s = r.x + r.y + r.z + r.w;
    for (int off = 32; off > 0; off >>= 1) s += __shfl_xor(s, off);
    if ((t & 63) == 0) reds[t >> 6] = s;
    __syncthreads();
    s = reds[0];
#pragma unroll
    for (int i = 1; i < 16; i++) s += reds[i];
    float inv = 1.f / s;
    r.x *= inv; r.y *= inv; r.z *= inv; r.w *= inv;
    *(float4*)(dst + t * 4) = r;
}

// ---------------- K3: lam_c partials --------------------------------------
__global__ __launch_bounds__(256) void k_lamc(float* __restrict__ ws) {
    int b  = blockIdx.x >> 4;
    int ch = blockIdx.x & 15;     // n-chunk
    int n0 = ch * 256;
    __shared__ float sms[16 * 256];
    int t = threadIdx.x;
    for (int i = 0; i < 16; i++) {
        int idx = t + i * 256;
        int k = idx >> 8, n = idx & 255;
        sms[idx] = ws[O_SM + ((size_t)(b * 16 + k)) * N_ + n0 + n];
    }
    __syncthreads();

    int v  = t & 63;
    int kg = __builtin_amdgcn_readfirstlane(t >> 6);
    float acc[4] = {0.f, 0.f, 0.f, 0.f};
    const float* vt = ws + O_VALT + ((size_t)b * N_ + n0) * 64 + v;
    for (int n = 0; n < 256; n++) {
        float val = vt[(size_t)n * 64];
#pragma unroll
        for (int j = 0; j < 4; j++) acc[j] += sms[(kg * 4 + j) * 256 + n] * val;
    }
#pragma unroll
    for (int j = 0; j < 4; j++)
        ws[O_LCP + ((size_t)(b * 16 + ch) * 16 + kg * 4 + j) * 64 + v] = acc[j];
}

// ---------------- K4: reduce lam_c partials -------------------------------
__global__ void k_lcred(float* __restrict__ ws) {
    int b = blockIdx.x, t = threadIdx.x;   // 1024 threads = 16k x 64v
    float s = 0.f;
    for (int c = 0; c < 16; c++)
        s += ws[O_LCP + ((size_t)(b * 16 + c)) * 1024 + t];
    ws[O_LC + (size_t)b * 1024 + t] = s;
}

// ---------------- K5: MFMA conv + y_p + y_c -------------------------------
__global__ __launch_bounds__(256, 4) void k_out(const float* __restrict__ wsc,
                                                float* __restrict__ out) {
    __shared__ _Float16 vt[2][4][18][88];   // 25344 B
    int ytile = blockIdx.x;                 // 0..7  (8 rows each)
    int vc    = blockIdx.y;                 // 0..15 (4 v each)
    int b     = blockIdx.z;
    int y0 = ytile * 8, v0 = vc * 4;
    int t = threadIdx.x;
    int w = t >> 6, l = t & 63;
    int g = l >> 4, nb = l & 15;

    // ---- stage value tile as f16, two copies (copy1 shifted left by 1) ----
    const float* vsrc = wsc + O_VALS + (size_t)b * 64 * N_;
    for (int idx = t; idx < 2 * 4 * 18 * 88; idx += 256) {
        int cp = idx / 6336, rem = idx % 6336;
        int v = rem / 1584, rem2 = rem % 1584;
        int r = rem2 / 88, c = rem2 % 88;
        int gy = y0 - 5 + r, gx = c - 8 + cp;
        _Float16 h = (_Float16)0.f;
        if ((unsigned)gy < 64u && (unsigned)gx < 64u)
            h = (_Float16)vsrc[(size_t)(v0 + v) * N_ + gy * 64 + gx];
        vt[cp][v][r][c] = h;
    }

    // ---- preload the 11 A-fragments (emb) --------------------------------
    half4 af[11];
    const _Float16* ef = (const _Float16*)(wsc + O_EMBT);
#pragma unroll
    for (int dy = 0; dy < 11; dy++) {
#pragma unroll
        for (int i = 0; i < 4; i++)
            af[dy][i] = ef[(dy * 16 + 4 * g + i) * 16 + nb];
    }

    __syncthreads();

    const char* ldsB = (const char*)&vt[0][0][0][0];

    for (int yy2 = 0; yy2 < 2; yy2++) {
        int yy = w * 2 + yy2;               // output row within tile (0..7)
        for (int xt = 0; xt < 4; xt++) {
            int pos = (y0 + yy) * 64 + xt * 16 + nb;
            // q[h][i] for this lane's 4 k-slices
            float q4[4][4];
            const float* qsrc = wsc + O_Q + (size_t)b * 64 * N_ + pos;
#pragma unroll
            for (int h = 0; h < 4; h++)
#pragma unroll
                for (int i = 0; i < 4; i++)
                    q4[h][i] = qsrc[(size_t)(h * 16 + 4 * g + i) * N_];

            int base = xt * 16 + nb + 4 * g + 3;    // window start (array col)
            int cp = base & 1, ub = base & ~1;

            for (int vp = 0; vp < 2; vp++) {
                int vA = vp * 2, vB = vp * 2 + 1;
                f32x4 dA = {0.f, 0.f, 0.f, 0.f}, dB = {0.f, 0.f, 0.f, 0.f};
                const char* pA = ldsB + (size_t)cp * 12672 + ((vA * 18 + yy) * 88 + ub) * 2;
                const char* pB = ldsB + (size_t)cp * 12672 + ((vB * 18 + yy) * 88 + ub) * 2;
#pragma unroll
                for (int dy = 0; dy < 11; dy++) {
                    union { uint u[2]; half4 h; } bA, bB;
                    bA.u[0] = *(const uint*)(pA + dy * 176);
                    bA.u[1] = *(const uint*)(pA + dy * 176 + 4);
                    bB.u[0] = *(const uint*)(pB + dy * 176);
                    bB.u[1] = *(const uint*)(pB + dy * 176 + 4);
                    dA = __builtin_amdgcn_mfma_f32_16x16x16f16(af[dy], bA.h, dA, 0, 0, 0);
                    dB = __builtin_amdgcn_mfma_f32_16x16x16f16(af[dy], bB.h, dB, 0, 0, 0);
                }
                // + lam_c, then contract with q, butterfly-reduce over k-groups
#pragma unroll
                for (int vv = 0; vv < 2; vv++) {
                    f32x4 d = vv ? dB : dA;
                    int vidx = vp * 2 + vv;
                    float lc0, lc1, lc2, lc3;
                    {
                        const float* lcp = wsc + O_LC + ((size_t)(b * 16 + 4 * g)) * 64 + v0 + vidx;
                        lc0 = lcp[0]; lc1 = lcp[64]; lc2 = lcp[128]; lc3 = lcp[192];
                    }
                    float d0 = d[0] + lc0, d1 = d[1] + lc1, d2 = d[2] + lc2, d3 = d[3] + lc3;
                    float ph[4];
#pragma unroll
                    for (int h = 0; h < 4; h++) {
                        float p = q4[h][0] * d0 + q4[h][1] * d1 + q4[h][2] * d2 + q4[h][3] * d3;
                        p += __shfl_xor(p, 16);
                        p += __shfl_xor(p, 32);
                        ph[h] = p;
                    }
                    float o = (g == 0) ? ph[0] : (g == 1) ? ph[1] : (g == 2) ? ph[2] : ph[3];
                    out[((size_t)(b * 256 + g * 64 + v0 + vidx)) * N_ + pos] = o;
                }
            }
        }
    }
}

extern "C" void kernel_launch(void* const* d_in, const int* in_sizes, int n_in,
                              void* d_out, int out_size, void* d_ws, size_t ws_size,
                              hipStream_t stream) {
    const float* x   = (const float*)d_in[0];
    const float* Wq  = (const float*)d_in[1];
    const float* qg  = (const float*)d_in[2];
    const float* qb  = (const float*)d_in[3];
    const float* qm  = (const float*)d_in[4];
    const float* qv  = (const float*)d_in[5];
    const float* Wk  = (const float*)d_in[6];
    const float* Wv  = (const float*)d_in[7];
    const float* vg  = (const float*)d_in[8];
    const float* vb  = (const float*)d_in[9];
    const float* vm  = (const float*)d_in[10];
    const float* vva = (const float*)d_in[11];
    const float* emb = (const float*)d_in[12];
    float* ws  = (float*)d_ws;
    float* out = (float*)d_out;

    k_prep<<<16, 256, 0, stream>>>(Wq, qg, qb, qm, qv, Wk, Wv, vg, vb, vm, vva, emb, ws);
    k_proj<<<dim3(32, 8), 256, 0, stream>>>(x, ws, ws);
    k_softmax<<<128, 1024, 0, stream>>>(ws);
    k_lamc<<<128, 256, 0, stream>>>(ws);
    k_lcred<<<8, 1024, 0, stream>>>(ws);
    k_out<<<dim3(8, 16, 8), 256, 0, stream>>>(ws, out);
}